// Round 3
// baseline (120.132 us; speedup 1.0000x reference)
//
#include <hip/hip_runtime.h>

#define ROW   8192
#define NT    256
#define CHUNK 32            // elements scanned sequentially per thread
#define G     8             // float4 groups per thread: ROW / (NT*4)

// tanh(d) = 1 - 2/(exp(2d)+1); robust at +/-inf (exp->inf gives 1, exp->0 gives -1)
__device__ __forceinline__ float fast_tanh(float d) {
    float e = __expf(2.0f * d);
    return 1.0f - 2.0f * __builtin_amdgcn_rcpf(e + 1.0f);
}

// XOR swizzle: logical float index -> physical LDS slot. Keeps both the
// coalesced-order (4t+k) accesses and the chunk-order (t*32+j) accesses at
// <=2-way bank aliasing (free). Flips only low 5 bits -> stays in [0,8192).
__device__ __forceinline__ int swz(int i) { return i ^ ((i >> 5) & 31); }

__global__ __launch_bounds__(NT) void diff_tanh_cumsum(const float* __restrict__ x,
                                                       float* __restrict__ out) {
    __shared__ float lds[ROW];          // 32 KB: holds tanh values, then prefixes
    __shared__ float wave_tot[NT / 64]; // per-wave totals for cross-wave scan

    const int t = threadIdx.x;
    const long long rb = (long long)blockIdx.x * ROW;

    // Phase 1: coalesced load, diff, tanh, swizzled LDS store
    #pragma unroll
    for (int g = 0; g < G; ++g) {
        const int i0 = (t + NT * g) * 4;
        float4 v = *reinterpret_cast<const float4*>(x + rb + i0);
        // previous element: neighbor lane's v.w; wave-leader fetches from global (L1 hit)
        float prev = __shfl_up(v.w, 1, 64);
        if ((t & 63) == 0 && i0 > 0) prev = x[rb + i0 - 1];
        float t0 = (i0 == 0) ? 0.0f : fast_tanh(v.x - prev); // d[0] forced to 0, tanh(0)=0
        float t1 = fast_tanh(v.y - v.x);
        float t2 = fast_tanh(v.z - v.y);
        float t3 = fast_tanh(v.w - v.z);
        lds[swz(i0 + 0)] = t0;
        lds[swz(i0 + 1)] = t1;
        lds[swz(i0 + 2)] = t2;
        lds[swz(i0 + 3)] = t3;
    }
    __syncthreads();

    // Phase 2: per-thread sequential inclusive scan of its contiguous 32-chunk.
    // physical(base+j) = base + (j ^ (t&31)) since base = t*32 has low-5 bits 0.
    const int base = t * CHUNK;
    const int bx = t & 31;
    float pref[CHUNK];
    float s = 0.0f;
    #pragma unroll
    for (int j = 0; j < CHUNK; ++j) {
        s += lds[base + (j ^ bx)];
        pref[j] = s;
    }

    // Phase 3: wave inclusive scan of thread totals, then cross-wave combine
    float ws = s;
    #pragma unroll
    for (int d = 1; d < 64; d <<= 1) {
        float o = __shfl_up(ws, d, 64);
        if ((t & 63) >= d) ws += o;
    }
    const int w = t >> 6;
    if ((t & 63) == 63) wave_tot[w] = ws;
    __syncthreads();
    float excl = ws - s;                       // exclusive offset within wave
    for (int i = 0; i < w; ++i) excl += wave_tot[i];

    // Phase 4: prefixes back to LDS (same slots this thread read; no race)
    #pragma unroll
    for (int j = 0; j < CHUNK; ++j)
        lds[base + (j ^ bx)] = excl + pref[j];
    __syncthreads();

    // Phase 5: coalesced float4 store
    #pragma unroll
    for (int g = 0; g < G; ++g) {
        const int i0 = (t + NT * g) * 4;
        float4 v;
        v.x = lds[swz(i0 + 0)];
        v.y = lds[swz(i0 + 1)];
        v.z = lds[swz(i0 + 2)];
        v.w = lds[swz(i0 + 3)];
        *reinterpret_cast<float4*>(out + rb + i0) = v;
    }
}

extern "C" void kernel_launch(void* const* d_in, const int* in_sizes, int n_in,
                              void* d_out, int out_size, void* d_ws, size_t ws_size,
                              hipStream_t stream) {
    const float* x = (const float*)d_in[0];
    float* out = (float*)d_out;
    const int rows = in_sizes[0] / ROW;   // 8192 rows of 8192 fp32
    diff_tanh_cumsum<<<rows, NT, 0, stream>>>(x, out);
}

// Round 4
// 109.490 us; speedup vs baseline: 1.0972x; 1.0972x over previous
//
#include <hip/hip_runtime.h>

#define ROW  8192
#define NT   256
#define NW   (NT / 64)      // 4 waves per block
#define G    8              // float4 groups per thread: ROW / (NT*4)

// tanh(d) = 1 - 2/(exp(2d)+1); robust at +/-inf (exp->inf -> 1, exp->0 -> -1)
__device__ __forceinline__ float fast_tanh(float d) {
    float e = __expf(2.0f * d);
    return 1.0f - 2.0f * __builtin_amdgcn_rcpf(e + 1.0f);
}

// Element mapping (coalesced): e = 1024*g + 4*t + k = 1024*g + 256*w + 4*l + k.
// Scan order decomposition: groups g (major) -> waves w -> lanes l -> k.
__global__ __launch_bounds__(NT) void diff_tanh_cumsum(const float* __restrict__ x,
                                                       float* __restrict__ out) {
    __shared__ float tot[NW * G];   // 128 B: per-(wave, group) totals

    const int t    = threadIdx.x;
    const int lane = t & 63;
    const int w    = t >> 6;
    const long long rb = (long long)blockIdx.x * ROW;

    // ---- Phase A: coalesced float4 loads, all issued up-front (MLP) ----
    float4 v[G];
    #pragma unroll
    for (int g = 0; g < G; ++g)
        v[g] = *reinterpret_cast<const float4*>(x + rb + (t + NT * g) * 4);

    // ---- Phase B: diff + tanh + inclusive scan within each float4 ----
    float4 p[G];   // inclusive prefix within the 4
    float  s[G];   // per-thread group sums
    #pragma unroll
    for (int g = 0; g < G; ++g) {
        const int i0 = (t + NT * g) * 4;
        // previous element: neighbor lane's v.w; wave leader fetches from
        // global (line already resident in L1/L2 from the coalesced loads)
        float prev = __shfl_up(v[g].w, 1, 64);
        if (lane == 0) prev = (i0 > 0) ? x[rb + i0 - 1] : v[g].x; // i0==0: d[0]=0
        float t0 = fast_tanh(v[g].x - prev);
        float t1 = fast_tanh(v[g].y - v[g].x);
        float t2 = fast_tanh(v[g].z - v[g].y);
        float t3 = fast_tanh(v[g].w - v[g].z);
        float q0 = t0;
        float q1 = q0 + t1;
        float q2 = q1 + t2;
        float q3 = q2 + t3;
        p[g] = make_float4(q0, q1, q2, q3);
        s[g] = q3;
    }

    // ---- Phase C: wave-inclusive scan of s[g] across lanes ----
    // (d outer, g inner: 8 independent shfl chains per step -> good ILP)
    float ws[G];
    #pragma unroll
    for (int g = 0; g < G; ++g) ws[g] = s[g];
    #pragma unroll
    for (int d = 1; d < 64; d <<= 1) {
        #pragma unroll
        for (int g = 0; g < G; ++g) {
            float o = __shfl_up(ws[g], d, 64);
            if (lane >= d) ws[g] += o;
        }
    }

    // ---- Phase D: single tiny LDS exchange of wave totals (ONE barrier) ----
    if (lane == 63) {
        #pragma unroll
        for (int g = 0; g < G; ++g) tot[w * G + g] = ws[g];
    }
    __syncthreads();

    // Global exclusive offset for (g, w, lane):
    //   sum of all earlier groups + earlier waves in this group + earlier lanes
    float run = 0.0f;
    float off[G];
    #pragma unroll
    for (int g = 0; g < G; ++g) {
        float wpre = 0.0f, gtot = 0.0f;
        #pragma unroll
        for (int ww = 0; ww < NW; ++ww) {
            float tv = tot[ww * G + g];   // broadcast read (no conflicts)
            gtot += tv;
            if (ww < w) wpre += tv;
        }
        off[g] = run + wpre + (ws[g] - s[g]);  // + lane-exclusive within wave
        run += gtot;
    }

    // ---- Phase E: add offsets, coalesced float4 store straight from regs ----
    #pragma unroll
    for (int g = 0; g < G; ++g) {
        float4 o;
        o.x = p[g].x + off[g];
        o.y = p[g].y + off[g];
        o.z = p[g].z + off[g];
        o.w = p[g].w + off[g];
        *reinterpret_cast<float4*>(out + rb + (t + NT * g) * 4) = o;
    }
}

extern "C" void kernel_launch(void* const* d_in, const int* in_sizes, int n_in,
                              void* d_out, int out_size, void* d_ws, size_t ws_size,
                              hipStream_t stream) {
    const float* x = (const float*)d_in[0];
    float* out = (float*)d_out;
    const int rows = in_sizes[0] / ROW;   // 8192 rows of 8192 fp32
    diff_tanh_cumsum<<<rows, NT, 0, stream>>>(x, out);
}

// Round 6
// 87.617 us; speedup vs baseline: 1.3711x; 1.2496x over previous
//
#include <hip/hip_runtime.h>

#define ROW  8192
#define NT   512
#define NW   (NT / 64)      // 8 waves per block
#define G    4              // float4 groups per thread: ROW / (NT*4)

typedef float f32x4 __attribute__((ext_vector_type(4)));  // native vector for nt-store

// tanh(d) = 1 - 2/(exp(2d)+1); robust at +/-inf (exp->inf -> 1, exp->0 -> -1)
__device__ __forceinline__ float fast_tanh(float d) {
    float e = __expf(2.0f * d);
    return 1.0f - 2.0f * __builtin_amdgcn_rcpf(e + 1.0f);
}

// Element mapping (coalesced): e = 2048*g + 4*t + k = 2048*g + 256*w + 4*l + k.
__global__ __launch_bounds__(NT) void diff_tanh_cumsum(const float* __restrict__ x,
                                                       float* __restrict__ out) {
    __shared__ float last[NW][G];   // lane-63 v.w per (wave, group): boundary exchange
    __shared__ float tot[NW][G];    // per-(wave, group) totals for cross-wave scan

    const int t    = threadIdx.x;
    const int lane = t & 63;
    const int w    = t >> 6;
    const long long rb = (long long)blockIdx.x * ROW;

    // ---- Phase A: coalesced float4 loads, all in flight at once ----
    f32x4 v[G];
    #pragma unroll
    for (int g = 0; g < G; ++g)
        v[g] = *reinterpret_cast<const f32x4*>(x + rb + (t + NT * g) * 4);

    // publish wave-boundary elements (no global refetch needed anywhere)
    if (lane == 63) {
        #pragma unroll
        for (int g = 0; g < G; ++g) last[w][g] = v[g].w;
    }
    __syncthreads();

    // ---- Phase B: diff + tanh + in-place inclusive scan within each float4 ----
    float s[G];   // per-thread group sums
    #pragma unroll
    for (int g = 0; g < G; ++g) {
        float prev = __shfl_up(v[g].w, 1, 64);
        if (lane == 0) {
            // prev element of e0 = 2048g + 256w: lane 63 of wave w-1 (same g),
            // or lane 63 of wave NW-1 of group g-1; for (0,0): d[0]=0 -> use v.x
            prev = (w > 0) ? last[w - 1][g]
                 : (g > 0) ? last[NW - 1][g - 1]
                           : v[g].x;
        }
        float t0 = fast_tanh(v[g].x - prev);
        float t1 = fast_tanh(v[g].y - v[g].x);
        float t2 = fast_tanh(v[g].z - v[g].y);
        float t3 = fast_tanh(v[g].w - v[g].z);
        v[g].x = t0;              // overwrite with inclusive prefix (reg reuse)
        v[g].y = v[g].x + t1;
        v[g].z = v[g].y + t2;
        v[g].w = v[g].z + t3;
        s[g]   = v[g].w;
    }

    // ---- Phase C: wave-inclusive scan of s[g] across lanes (4 chains, ILP) ----
    float ws[G];
    #pragma unroll
    for (int g = 0; g < G; ++g) ws[g] = s[g];
    #pragma unroll
    for (int d = 1; d < 64; d <<= 1) {
        #pragma unroll
        for (int g = 0; g < G; ++g) {
            float o = __shfl_up(ws[g], d, 64);
            if (lane >= d) ws[g] += o;
        }
    }

    // ---- Phase D: tiny LDS exchange of wave totals, one barrier ----
    if (lane == 63) {
        #pragma unroll
        for (int g = 0; g < G; ++g) tot[w][g] = ws[g];
    }
    __syncthreads();

    float run = 0.0f;
    float off[G];
    #pragma unroll
    for (int g = 0; g < G; ++g) {
        float wpre = 0.0f, gtot = 0.0f;
        #pragma unroll
        for (int ww = 0; ww < NW; ++ww) {
            float tv = tot[ww][g];        // broadcast read, no conflicts
            gtot += tv;
            if (ww < w) wpre += tv;       // w is wave-uniform -> cheap
        }
        off[g] = run + wpre + (ws[g] - s[g]);  // + lane-exclusive within wave
        run += gtot;
    }

    // ---- Phase E: add offsets, nontemporal coalesced float4 store ----
    #pragma unroll
    for (int g = 0; g < G; ++g) {
        f32x4 o;
        o.x = v[g].x + off[g];
        o.y = v[g].y + off[g];
        o.z = v[g].z + off[g];
        o.w = v[g].w + off[g];
        __builtin_nontemporal_store(o, reinterpret_cast<f32x4*>(out + rb + (t + NT * g) * 4));
    }
}

extern "C" void kernel_launch(void* const* d_in, const int* in_sizes, int n_in,
                              void* d_out, int out_size, void* d_ws, size_t ws_size,
                              hipStream_t stream) {
    const float* x = (const float*)d_in[0];
    float* out = (float*)d_out;
    const int rows = in_sizes[0] / ROW;   // 8192 rows of 8192 fp32
    diff_tanh_cumsum<<<rows, NT, 0, stream>>>(x, out);
}